// Round 3
// baseline (166.497 us; speedup 1.0000x reference)
//
#include <hip/hip_runtime.h>
#include <cstdint>
#include <cstddef>

#define B 4096
#define D 128
#define MARGIN_F 0.2f
#define CW 256            // per-row candidate capacity
#define ROWS 16           // rows per block
#define SSTR 4104         // key-strip stride (ushorts): rows 16B-aligned, bank-skewed

typedef short bf16x8 __attribute__((ext_vector_type(8)));
typedef float f32x4 __attribute__((ext_vector_type(4)));
typedef uint32_t u32x4 __attribute__((ext_vector_type(4)));

// order-preserving float->uint (ascending uint == ascending float)
__device__ __forceinline__ uint32_t xform_key(float f) {
    uint32_t u = __float_as_uint(f);
    return u ^ (uint32_t)((((int32_t)u) >> 31) | 0x80000000);
}
// decode 16-bit truncated key (bucket center under round-to-nearest encode)
__device__ __forceinline__ float unxform16(uint32_t k16) {
    uint32_t u = k16 << 16;
    u = (u & 0x80000000u) ? (u ^ 0x80000000u) : ~u;
    return __uint_as_float(u);
}
__device__ __forceinline__ unsigned short f2bf(float f) {   // round-nearest-even
    uint32_t u = __float_as_uint(f);
    return (unsigned short)((u + 0x7FFFu + ((u >> 16) & 1u)) >> 16);
}

// fused: zero out, sq[i] = ||R[i]||^2, R -> Rb (bf16 rne)
__global__ __launch_bounds__(256) void prep_kernel(const float* __restrict__ R,
                                                   float* __restrict__ sq,
                                                   unsigned short* __restrict__ Rb,
                                                   float* __restrict__ out) {
    if (blockIdx.x == 0 && threadIdx.x == 0) out[0] = 0.0f;
    int wave = threadIdx.x >> 6;
    int lane = threadIdx.x & 63;
    int row  = blockIdx.x * 4 + wave;
    const float2* R2 = (const float2*)R + (size_t)row * (D / 2);
    float2 v = R2[lane];
    ushort2 o; o.x = f2bf(v.x); o.y = f2bf(v.y);
    *(ushort2*)(Rb + (size_t)row * D + lane * 2) = o;
    float s = v.x * v.x + v.y * v.y;
#pragma unroll
    for (int off = 32; off > 0; off >>= 1) s += __shfl_down(s, off);
    if (lane == 0) sq[row] = s;
}

// FUSED: 16 rows/block, 512 threads (8 waves) -- the proven codegen regime
// (R1/R2 lesson: 1024 threads makes the allocator crunch VGPR 96->52 and
// re-read kv from LDS; unrecoverable via attributes).
// R3 rewrite: phase 2's two serial-LDS chains removed:
//  - exact-rank: chunked ds_read_b128 BROADCAST scan of cand_c (8 cands/chunk,
//    pipelined) vs ~450 serial scalar reads; ranks applied per-owning-lane.
//  - below-T matches: detected from register-resident owned candidates +
//    ballot/ffs extraction (no LDS find-scan); 8 pivots per kv flush.
__global__ __launch_bounds__(512) void fused_loss(const unsigned short* __restrict__ Rb,
                                                  const float* __restrict__ sq,
                                                  const int* __restrict__ labels,
                                                  float* __restrict__ out) {
    __shared__ unsigned short S[ROWS * SSTR];      // 131,328 B key strip
    __shared__ uint32_t cand_c[ROWS][CW];          // 16 KB: comb | (match<<31)
    __shared__ int cnt[ROWS];

    const int tid  = threadIdx.x;
    const int wid  = tid >> 6, lane = tid & 63;
    const int q    = lane >> 4, t = lane & 15;
    const int r0   = blockIdx.x * ROWS;

    // zero cand_c (pad-safety for the chunked rank scan) + cnt
    {
        uint32_t* cz = &cand_c[0][0];
#pragma unroll
        for (int c = 0; c < (ROWS * CW) / 512; ++c)
            cz[tid + c * 512] = 0u;
    }
    if (tid < ROWS) cnt[tid] = 0;

    // ---- phase 1: A fragments for the block's 16 rows (held in registers)
    bf16x8 af[4];
    const unsigned short* baseA = Rb + (size_t)(r0 + t) * D + q * 8;
#pragma unroll
    for (int kq = 0; kq < 4; ++kq)
        af[kq] = *(const bf16x8*)(baseA + kq * 32);

    float sqa[4]; int la[4];                       // epilogue row scalars (row = q*4+rr)
#pragma unroll
    for (int rr = 0; rr < 4; ++rr) {
        sqa[rr] = sq[r0 + q * 4 + rr];
        la[rr]  = labels[r0 + q * 4 + rr];
    }

    // 256 j-tiles of 16 cols; 8 waves -> 32 tiles/wave
    for (int i = 0; i < 32; ++i) {
        const int jt  = wid * 32 + i;
        const int col = jt * 16 + t;
        const unsigned short* baseB = Rb + (size_t)col * D + q * 8;
        bf16x8 bfr[4];
#pragma unroll
        for (int kq = 0; kq < 4; ++kq)
            bfr[kq] = *(const bf16x8*)(baseB + kq * 32);
        f32x4 acc = (f32x4)0.0f;
#pragma unroll
        for (int kq = 0; kq < 4; ++kq)
            acc = __builtin_amdgcn_mfma_f32_16x16x32_bf16(af[kq], bfr[kq], acc, 0, 0, 0);

        const float sqc = sq[col];
        const int   lc  = labels[col];
#pragma unroll
        for (int rr = 0; rr < 4; ++rr) {           // D: row = q*4+rr, col = t
            float g  = acc[rr];
            float d2 = fmaxf(sqa[rr] + sqc - 2.0f * g, 0.0f);
            float dist = (d2 > 0.0f) ? sqrtf(d2) : 0.0f;
            float s = -dist + ((la[rr] == lc) ? 0.0f : MARGIN_F);
            uint32_t key = xform_key(s);           // sim <= 0.2 -> no ovf on +0x8000
            S[(q * 4 + rr) * SSTR + col] = (unsigned short)((key + 0x8000u) >> 16);
        }
    }
    __syncthreads();                               // strip + zeroed cand_c visible

    // ---- phase 2: each wave owns 2 rows; keys kv[8] from LDS (b128, aligned)
    float facc = 0.0f;
    const int4* lv = (const int4*)labels;

    for (int rr2 = 0; rr2 < 2; ++rr2) {
        const int row  = wid * 2 + rr2;
        const int grow = r0 + row;
        const int li   = labels[grow];

        u32x4 kv[8];
#pragma unroll
        for (int qq = 0; qq < 8; ++qq)
            kv[qq] = *(u32x4*)(&S[row * SSTR + (qq * 64 + lane) * 8]);

        uint64_t mbits = 0;
        uint32_t t1 = 0, t2 = 0;
#pragma unroll
        for (int qq = 0; qq < 8; ++qq) {
            const int lb = (qq * 64 + lane) * 2;
            int4 la4 = lv[lb], lc4 = lv[lb + 1];
            uint32_t u[8] = {kv[qq].x & 0xFFFFu, kv[qq].x >> 16,
                             kv[qq].y & 0xFFFFu, kv[qq].y >> 16,
                             kv[qq].z & 0xFFFFu, kv[qq].z >> 16,
                             kv[qq].w & 0xFFFFu, kv[qq].w >> 16};
#pragma unroll
            for (int c = 0; c < 8; ++c) {
                uint32_t mn = min(t1, u[c]);
                t1 = max(t1, u[c]);
                t2 = max(t2, mn);
            }
            mbits |= (uint64_t)(la4.x == li) << (qq * 8 + 0);
            mbits |= (uint64_t)(la4.y == li) << (qq * 8 + 1);
            mbits |= (uint64_t)(la4.z == li) << (qq * 8 + 2);
            mbits |= (uint64_t)(la4.w == li) << (qq * 8 + 3);
            mbits |= (uint64_t)(lc4.x == li) << (qq * 8 + 4);
            mbits |= (uint64_t)(lc4.y == li) << (qq * 8 + 5);
            mbits |= (uint64_t)(lc4.z == li) << (qq * 8 + 6);
            mbits |= (uint64_t)(lc4.w == li) << (qq * 8 + 7);
        }

        int kloc = __popcll(mbits);
#pragma unroll
        for (int off = 32; off > 0; off >>= 1) kloc += __shfl_xor(kloc, off);
        const int k = kloc;
        const float kf = (float)k;

        // ballot binary search: T = k-th largest of 128-subset (<= true k-th)
        const int kneed = min(k, 128);
        uint32_t T = 0;
#pragma unroll
        for (int b = 15; b >= 0; --b) {
            uint32_t g = T | (1u << b);
            int c = __popcll(__ballot(t1 >= g)) + __popcll(__ballot(t2 >= g));
            if (c >= kneed) T = g;
        }
        const uint32_t combT = T << 12;

        // gather candidates = {u >= T} U {matches}; comb = (u<<12)|(4095-j)
#pragma unroll
        for (int qq = 0; qq < 8; ++qq) {
            uint32_t u[8] = {kv[qq].x & 0xFFFFu, kv[qq].x >> 16,
                             kv[qq].y & 0xFFFFu, kv[qq].y >> 16,
                             kv[qq].z & 0xFFFFu, kv[qq].z >> 16,
                             kv[qq].w & 0xFFFFu, kv[qq].w >> 16};
            int jb = (qq * 64 + lane) * 8;
#pragma unroll
            for (int c = 0; c < 8; ++c) {
                int e = qq * 8 + c;
                uint32_t m = (uint32_t)((mbits >> e) & 1);
                if (u[c] >= T || m) {
                    int p = atomicAdd(&cnt[row], 1);
                    if (p < CW)
                        cand_c[row][p] = (u[c] << 12) | (uint32_t)(4095 - (jb + c)) | (m << 31);
                }
            }
        }
        const int ncand = min(cnt[row], CW);

        // ---- owned candidates -> registers (slots lane, lane+64, +128, +192)
        uint32_t cr0 = cand_c[row][lane];
        uint32_t cr1 = cand_c[row][lane + 64];
        uint32_t cr2 = cand_c[row][lane + 128];
        uint32_t cr3 = cand_c[row][lane + 192];
        uint32_t mycomb[4] = {cr0 & 0x7FFFFFFFu, cr1 & 0x7FFFFFFFu,
                              cr2 & 0x7FFFFFFFu, cr3 & 0x7FFFFFFFu};
        int mym[4]  = {(int)(cr0 >> 31), (int)(cr1 >> 31),
                       (int)(cr2 >> 31), (int)(cr3 >> 31)};
        int myok[4] = {lane < ncand, lane + 64 < ncand,
                       lane + 128 < ncand, lane + 192 < ncand};
        int myc[4]  = {0, 0, 0, 0};

        // ---- exact-rank: chunked broadcast scan (8 cands / 2 b128 per chunk)
        const int npad = (ncand + 7) & ~7;
        for (int c0i = 0; c0i < npad; c0i += 8) {
            u32x4 a = *(const u32x4*)&cand_c[row][c0i];
            u32x4 b = *(const u32x4*)&cand_c[row][c0i + 4];
            uint32_t vv[8] = {a.x, a.y, a.z, a.w, b.x, b.y, b.z, b.w};
#pragma unroll
            for (int e = 0; e < 8; ++e) {
                uint32_t vm = vv[e] & 0x7FFFFFFFu;
#pragma unroll
                for (int j = 0; j < 4; ++j)
                    myc[j] += (vm > mycomb[j]) ? 1 : 0;
            }
        }

        // apply above-T terms per owned candidate (each owned by one lane)
#pragma unroll
        for (int j = 0; j < 4; ++j) {
            if (myok[j] && mycomb[j] >= combT) {
                int rank = 1 + myc[j];
                float v = unxform16(mycomb[j] >> 12);
                if (!mym[j] && rank <= k)
                    facc += v * (0.5f + ((kf - (float)rank + 1.0f) / kf) * 0.5f);
                else if (mym[j] && rank > k)
                    facc -= v * (0.5f + (((float)rank - kf) / (float)(B - k)) * 0.5f);
            }
        }

        // ---- below-T matches (rank > k guaranteed): detect from registers,
        // extract via ballot, flush up to 8 pivots per full-row kv scan
        uint32_t p0 = 0xFFFFFFFFu, p1 = 0xFFFFFFFFu, p2 = 0xFFFFFFFFu, p3 = 0xFFFFFFFFu;
        uint32_t p4 = 0xFFFFFFFFu, p5 = 0xFFFFFFFFu, p6 = 0xFFFFFFFFu, p7 = 0xFFFFFFFFu;

        auto flush8 = [&](int npv) {
            int c0 = 0, c1 = 0, c2 = 0, c3 = 0, c4 = 0, c5 = 0, c6 = 0, c7 = 0;
#pragma unroll
            for (int qq = 0; qq < 8; ++qq) {
                uint32_t u[8] = {kv[qq].x & 0xFFFFu, kv[qq].x >> 16,
                                 kv[qq].y & 0xFFFFu, kv[qq].y >> 16,
                                 kv[qq].z & 0xFFFFu, kv[qq].z >> 16,
                                 kv[qq].w & 0xFFFFu, kv[qq].w >> 16};
                int jb = (qq * 64 + lane) * 8;
#pragma unroll
                for (int cc = 0; cc < 8; ++cc) {
                    uint32_t ce = (u[cc] << 12) | (uint32_t)(4095 - (jb + cc));
                    c0 += (ce > p0) ? 1 : 0;  c1 += (ce > p1) ? 1 : 0;
                    c2 += (ce > p2) ? 1 : 0;  c3 += (ce > p3) ? 1 : 0;
                    c4 += (ce > p4) ? 1 : 0;  c5 += (ce > p5) ? 1 : 0;
                    c6 += (ce > p6) ? 1 : 0;  c7 += (ce > p7) ? 1 : 0;
                }
            }
#pragma unroll
            for (int off = 32; off > 0; off >>= 1) {
                c0 += __shfl_xor(c0, off); c1 += __shfl_xor(c1, off);
                c2 += __shfl_xor(c2, off); c3 += __shfl_xor(c3, off);
                c4 += __shfl_xor(c4, off); c5 += __shfl_xor(c5, off);
                c6 += __shfl_xor(c6, off); c7 += __shfl_xor(c7, off);
            }
            if (lane == 0) {
                if (npv > 0) facc -= unxform16(p0 >> 12) * (0.5f + (((float)(1 + c0) - kf) / (float)(B - k)) * 0.5f);
                if (npv > 1) facc -= unxform16(p1 >> 12) * (0.5f + (((float)(1 + c1) - kf) / (float)(B - k)) * 0.5f);
                if (npv > 2) facc -= unxform16(p2 >> 12) * (0.5f + (((float)(1 + c2) - kf) / (float)(B - k)) * 0.5f);
                if (npv > 3) facc -= unxform16(p3 >> 12) * (0.5f + (((float)(1 + c3) - kf) / (float)(B - k)) * 0.5f);
                if (npv > 4) facc -= unxform16(p4 >> 12) * (0.5f + (((float)(1 + c4) - kf) / (float)(B - k)) * 0.5f);
                if (npv > 5) facc -= unxform16(p5 >> 12) * (0.5f + (((float)(1 + c5) - kf) / (float)(B - k)) * 0.5f);
                if (npv > 6) facc -= unxform16(p6 >> 12) * (0.5f + (((float)(1 + c6) - kf) / (float)(B - k)) * 0.5f);
                if (npv > 7) facc -= unxform16(p7 >> 12) * (0.5f + (((float)(1 + c7) - kf) / (float)(B - k)) * 0.5f);
            }
            p0 = p1 = p2 = p3 = p4 = p5 = p6 = p7 = 0xFFFFFFFFu;
        };

        int np = 0;
#pragma unroll
        for (int j = 0; j < 4; ++j) {
            uint64_t mg = __ballot(myok[j] && mym[j] && (mycomb[j] < combT));
            while (mg) {
                int src = __ffsll((unsigned long long)mg) - 1;
                mg &= mg - 1;
                uint32_t pc;
                if (j == 0)      pc = __shfl(mycomb[0], src);
                else if (j == 1) pc = __shfl(mycomb[1], src);
                else if (j == 2) pc = __shfl(mycomb[2], src);
                else             pc = __shfl(mycomb[3], src);
                switch (np) {
                    case 0: p0 = pc; break; case 1: p1 = pc; break;
                    case 2: p2 = pc; break; case 3: p3 = pc; break;
                    case 4: p4 = pc; break; case 5: p5 = pc; break;
                    case 6: p6 = pc; break; default: p7 = pc; break;
                }
                ++np;
                if (np == 8) { flush8(8); np = 0; }
            }
        }
        if (np > 0) flush8(np);
    }

#pragma unroll
    for (int off = 32; off > 0; off >>= 1) facc += __shfl_xor(facc, off);
    if (lane == 0) atomicAdd(out, facc);
}

extern "C" void kernel_launch(void* const* d_in, const int* in_sizes, int n_in,
                              void* d_out, int out_size, void* d_ws, size_t ws_size,
                              hipStream_t stream) {
    const float* R      = (const float*)d_in[0];
    const int*   labels = (const int*)d_in[1];
    float* out = (float*)d_out;

    float*          sq = (float*)d_ws;                               // 16 KB
    unsigned short* Rb = (unsigned short*)((char*)d_ws + 16 * 1024); // 1 MB

    hipLaunchKernelGGL(prep_kernel, dim3(B / 4), dim3(256), 0, stream, R, sq, Rb, out);
    hipLaunchKernelGGL(fused_loss, dim3(B / ROWS), dim3(512), 0, stream,
                       Rb, sq, labels, out);
}

// Round 4
// 134.134 us; speedup vs baseline: 1.2413x; 1.2413x over previous
//
#include <hip/hip_runtime.h>
#include <cstdint>
#include <cstddef>

#define B 4096
#define D 128
#define MARGIN_F 0.2f
#define CW 256            // per-row candidate capacity
#define ROWS 16           // rows per block
#define SSTR 4104         // key-strip stride (ushorts): rows 16B-aligned, bank-skewed

typedef short bf16x8 __attribute__((ext_vector_type(8)));
typedef float f32x4 __attribute__((ext_vector_type(4)));
typedef uint32_t u32x4 __attribute__((ext_vector_type(4)));

// order-preserving float->uint (ascending uint == ascending float)
__device__ __forceinline__ uint32_t xform_key(float f) {
    uint32_t u = __float_as_uint(f);
    return u ^ (uint32_t)((((int32_t)u) >> 31) | 0x80000000);
}
// decode 16-bit truncated key (bucket center under round-to-nearest encode)
__device__ __forceinline__ float unxform16(uint32_t k16) {
    uint32_t u = k16 << 16;
    u = (u & 0x80000000u) ? (u ^ 0x80000000u) : ~u;
    return __uint_as_float(u);
}
__device__ __forceinline__ unsigned short f2bf(float f) {   // round-nearest-even
    uint32_t u = __float_as_uint(f);
    return (unsigned short)((u + 0x7FFFu + ((u >> 16) & 1u)) >> 16);
}

// fused: zero out, sq[i] = ||R[i]||^2, R -> Rb (bf16 rne)
__global__ __launch_bounds__(256) void prep_kernel(const float* __restrict__ R,
                                                   float* __restrict__ sq,
                                                   unsigned short* __restrict__ Rb,
                                                   float* __restrict__ out) {
    if (blockIdx.x == 0 && threadIdx.x == 0) out[0] = 0.0f;
    int wave = threadIdx.x >> 6;
    int lane = threadIdx.x & 63;
    int row  = blockIdx.x * 4 + wave;
    const float2* R2 = (const float2*)R + (size_t)row * (D / 2);
    float2 v = R2[lane];
    ushort2 o; o.x = f2bf(v.x); o.y = f2bf(v.y);
    *(ushort2*)(Rb + (size_t)row * D + lane * 2) = o;
    float s = v.x * v.x + v.y * v.y;
#pragma unroll
    for (int off = 32; off > 0; off >>= 1) s += __shfl_down(s, off);
    if (lane == 0) sq[row] = s;
}

// FUSED: 16 rows/block, 512 threads (8 waves).
// R4: R3's two algorithmic wins kept, spill removed (R3 lesson: WRITE_SIZE
// 64KB->42MB = scratch):
//  - kv[8]'s live range now ENDS at the gather; the below-T flush re-reads
//    the strip from S one u32x4 at a time (-32 regs across the rank scan).
//  - 4 pivots per flush instead of 8 (-8 regs); ~2 flushes/row vs 1.
__global__ __launch_bounds__(512) void fused_loss(const unsigned short* __restrict__ Rb,
                                                  const float* __restrict__ sq,
                                                  const int* __restrict__ labels,
                                                  float* __restrict__ out) {
    __shared__ unsigned short S[ROWS * SSTR];      // 131,328 B key strip
    __shared__ uint32_t cand_c[ROWS][CW];          // 16 KB: comb | (match<<31)
    __shared__ int cnt[ROWS];

    const int tid  = threadIdx.x;
    const int wid  = tid >> 6, lane = tid & 63;
    const int q    = lane >> 4, t = lane & 15;
    const int r0   = blockIdx.x * ROWS;

    // zero cand_c (pad-safety for the chunked rank scan) + cnt
    {
        uint32_t* cz = &cand_c[0][0];
#pragma unroll
        for (int c = 0; c < (ROWS * CW) / 512; ++c)
            cz[tid + c * 512] = 0u;
    }
    if (tid < ROWS) cnt[tid] = 0;

    // ---- phase 1: A fragments for the block's 16 rows (held in registers)
    bf16x8 af[4];
    const unsigned short* baseA = Rb + (size_t)(r0 + t) * D + q * 8;
#pragma unroll
    for (int kq = 0; kq < 4; ++kq)
        af[kq] = *(const bf16x8*)(baseA + kq * 32);

    float sqa[4]; int la[4];                       // epilogue row scalars (row = q*4+rr)
#pragma unroll
    for (int rr = 0; rr < 4; ++rr) {
        sqa[rr] = sq[r0 + q * 4 + rr];
        la[rr]  = labels[r0 + q * 4 + rr];
    }

    // 256 j-tiles of 16 cols; 8 waves -> 32 tiles/wave
    for (int i = 0; i < 32; ++i) {
        const int jt  = wid * 32 + i;
        const int col = jt * 16 + t;
        const unsigned short* baseB = Rb + (size_t)col * D + q * 8;
        bf16x8 bfr[4];
#pragma unroll
        for (int kq = 0; kq < 4; ++kq)
            bfr[kq] = *(const bf16x8*)(baseB + kq * 32);
        f32x4 acc = (f32x4)0.0f;
#pragma unroll
        for (int kq = 0; kq < 4; ++kq)
            acc = __builtin_amdgcn_mfma_f32_16x16x32_bf16(af[kq], bfr[kq], acc, 0, 0, 0);

        const float sqc = sq[col];
        const int   lc  = labels[col];
#pragma unroll
        for (int rr = 0; rr < 4; ++rr) {           // D: row = q*4+rr, col = t
            float g  = acc[rr];
            float d2 = fmaxf(sqa[rr] + sqc - 2.0f * g, 0.0f);
            float dist = (d2 > 0.0f) ? sqrtf(d2) : 0.0f;
            float s = -dist + ((la[rr] == lc) ? 0.0f : MARGIN_F);
            uint32_t key = xform_key(s);           // sim <= 0.2 -> no ovf on +0x8000
            S[(q * 4 + rr) * SSTR + col] = (unsigned short)((key + 0x8000u) >> 16);
        }
    }
    __syncthreads();                               // strip + zeroed cand_c visible

    // ---- phase 2: each wave owns 2 rows
    float facc = 0.0f;
    const int4* lv = (const int4*)labels;

    for (int rr2 = 0; rr2 < 2; ++rr2) {
        const int row  = wid * 2 + rr2;
        const int grow = r0 + row;
        const int li   = labels[grow];

        uint64_t mbits = 0;
        uint32_t t1 = 0, t2 = 0;

        {   // kv live range: this scope only (load -> minmax/mbits -> gather)
            u32x4 kv[8];
#pragma unroll
            for (int qq = 0; qq < 8; ++qq)
                kv[qq] = *(u32x4*)(&S[row * SSTR + (qq * 64 + lane) * 8]);

#pragma unroll
            for (int qq = 0; qq < 8; ++qq) {
                const int lb = (qq * 64 + lane) * 2;
                int4 la4 = lv[lb], lc4 = lv[lb + 1];
                uint32_t u[8] = {kv[qq].x & 0xFFFFu, kv[qq].x >> 16,
                                 kv[qq].y & 0xFFFFu, kv[qq].y >> 16,
                                 kv[qq].z & 0xFFFFu, kv[qq].z >> 16,
                                 kv[qq].w & 0xFFFFu, kv[qq].w >> 16};
#pragma unroll
                for (int c = 0; c < 8; ++c) {
                    uint32_t mn = min(t1, u[c]);
                    t1 = max(t1, u[c]);
                    t2 = max(t2, mn);
                }
                mbits |= (uint64_t)(la4.x == li) << (qq * 8 + 0);
                mbits |= (uint64_t)(la4.y == li) << (qq * 8 + 1);
                mbits |= (uint64_t)(la4.z == li) << (qq * 8 + 2);
                mbits |= (uint64_t)(la4.w == li) << (qq * 8 + 3);
                mbits |= (uint64_t)(lc4.x == li) << (qq * 8 + 4);
                mbits |= (uint64_t)(lc4.y == li) << (qq * 8 + 5);
                mbits |= (uint64_t)(lc4.z == li) << (qq * 8 + 6);
                mbits |= (uint64_t)(lc4.w == li) << (qq * 8 + 7);
            }

            int kloc = __popcll(mbits);
#pragma unroll
            for (int off = 32; off > 0; off >>= 1) kloc += __shfl_xor(kloc, off);
            const int k0 = kloc;

            // ballot binary search: T = k-th largest of 128-subset
            const int kneed = min(k0, 128);
            uint32_t T = 0;
#pragma unroll
            for (int b = 15; b >= 0; --b) {
                uint32_t g = T | (1u << b);
                int c = __popcll(__ballot(t1 >= g)) + __popcll(__ballot(t2 >= g));
                if (c >= kneed) T = g;
            }
            t1 = T;  // reuse t1 as T carrier out of scope
            t2 = (uint32_t)k0;

            // gather candidates = {u >= T} U {matches}; comb = (u<<12)|(4095-j)
#pragma unroll
            for (int qq = 0; qq < 8; ++qq) {
                uint32_t u[8] = {kv[qq].x & 0xFFFFu, kv[qq].x >> 16,
                                 kv[qq].y & 0xFFFFu, kv[qq].y >> 16,
                                 kv[qq].z & 0xFFFFu, kv[qq].z >> 16,
                                 kv[qq].w & 0xFFFFu, kv[qq].w >> 16};
                int jb = (qq * 64 + lane) * 8;
#pragma unroll
                for (int c = 0; c < 8; ++c) {
                    int e = qq * 8 + c;
                    uint32_t m = (uint32_t)((mbits >> e) & 1);
                    if (u[c] >= t1 || m) {
                        int p = atomicAdd(&cnt[row], 1);
                        if (p < CW)
                            cand_c[row][p] = (u[c] << 12) | (uint32_t)(4095 - (jb + c)) | (m << 31);
                    }
                }
            }
        }   // kv dead here

        const uint32_t T = t1;
        const int k = (int)t2;
        const float kf = (float)k;
        const uint32_t combT = T << 12;
        const int ncand = min(cnt[row], CW);

        // ---- owned candidates -> registers (slots lane, lane+64, +128, +192)
        uint32_t cr0 = cand_c[row][lane];
        uint32_t cr1 = cand_c[row][lane + 64];
        uint32_t cr2 = cand_c[row][lane + 128];
        uint32_t cr3 = cand_c[row][lane + 192];
        uint32_t mycomb[4] = {cr0 & 0x7FFFFFFFu, cr1 & 0x7FFFFFFFu,
                              cr2 & 0x7FFFFFFFu, cr3 & 0x7FFFFFFFu};
        int mym[4]  = {(int)(cr0 >> 31), (int)(cr1 >> 31),
                       (int)(cr2 >> 31), (int)(cr3 >> 31)};
        int myok[4] = {lane < ncand, lane + 64 < ncand,
                       lane + 128 < ncand, lane + 192 < ncand};
        int myc[4]  = {0, 0, 0, 0};

        // ---- exact-rank: chunked broadcast scan (8 cands / 2 b128 per chunk)
        const int npad = (ncand + 7) & ~7;
        for (int c0i = 0; c0i < npad; c0i += 8) {
            u32x4 a = *(const u32x4*)&cand_c[row][c0i];
            u32x4 b = *(const u32x4*)&cand_c[row][c0i + 4];
            uint32_t vv[8] = {a.x, a.y, a.z, a.w, b.x, b.y, b.z, b.w};
#pragma unroll
            for (int e = 0; e < 8; ++e) {
                uint32_t vm = vv[e] & 0x7FFFFFFFu;
#pragma unroll
                for (int j = 0; j < 4; ++j)
                    myc[j] += (vm > mycomb[j]) ? 1 : 0;
            }
        }

        // apply above-T terms per owned candidate (each owned by one lane)
#pragma unroll
        for (int j = 0; j < 4; ++j) {
            if (myok[j] && mycomb[j] >= combT) {
                int rank = 1 + myc[j];
                float v = unxform16(mycomb[j] >> 12);
                if (!mym[j] && rank <= k)
                    facc += v * (0.5f + ((kf - (float)rank + 1.0f) / kf) * 0.5f);
                else if (mym[j] && rank > k)
                    facc -= v * (0.5f + (((float)rank - kf) / (float)(B - k)) * 0.5f);
            }
        }

        // ---- below-T matches (rank > k guaranteed): detect from registers,
        // extract via ballot, flush up to 4 pivots per strip re-scan
        uint32_t p0 = 0xFFFFFFFFu, p1 = 0xFFFFFFFFu, p2 = 0xFFFFFFFFu, p3 = 0xFFFFFFFFu;

        auto flush4 = [&](int npv) {
            int c0 = 0, c1 = 0, c2 = 0, c3 = 0;
#pragma unroll
            for (int qq = 0; qq < 8; ++qq) {
                u32x4 kq = *(const u32x4*)(&S[row * SSTR + (qq * 64 + lane) * 8]);
                uint32_t u[8] = {kq.x & 0xFFFFu, kq.x >> 16,
                                 kq.y & 0xFFFFu, kq.y >> 16,
                                 kq.z & 0xFFFFu, kq.z >> 16,
                                 kq.w & 0xFFFFu, kq.w >> 16};
                int jb = (qq * 64 + lane) * 8;
#pragma unroll
                for (int cc = 0; cc < 8; ++cc) {
                    uint32_t ce = (u[cc] << 12) | (uint32_t)(4095 - (jb + cc));
                    c0 += (ce > p0) ? 1 : 0;  c1 += (ce > p1) ? 1 : 0;
                    c2 += (ce > p2) ? 1 : 0;  c3 += (ce > p3) ? 1 : 0;
                }
            }
#pragma unroll
            for (int off = 32; off > 0; off >>= 1) {
                c0 += __shfl_xor(c0, off); c1 += __shfl_xor(c1, off);
                c2 += __shfl_xor(c2, off); c3 += __shfl_xor(c3, off);
            }
            if (lane == 0) {
                if (npv > 0) facc -= unxform16(p0 >> 12) * (0.5f + (((float)(1 + c0) - kf) / (float)(B - k)) * 0.5f);
                if (npv > 1) facc -= unxform16(p1 >> 12) * (0.5f + (((float)(1 + c1) - kf) / (float)(B - k)) * 0.5f);
                if (npv > 2) facc -= unxform16(p2 >> 12) * (0.5f + (((float)(1 + c2) - kf) / (float)(B - k)) * 0.5f);
                if (npv > 3) facc -= unxform16(p3 >> 12) * (0.5f + (((float)(1 + c3) - kf) / (float)(B - k)) * 0.5f);
            }
            p0 = p1 = p2 = p3 = 0xFFFFFFFFu;
        };

        int np = 0;
#pragma unroll
        for (int j = 0; j < 4; ++j) {
            uint64_t mg = __ballot(myok[j] && mym[j] && (mycomb[j] < combT));
            while (mg) {
                int src = __ffsll((unsigned long long)mg) - 1;
                mg &= mg - 1;
                uint32_t pc;
                if (j == 0)      pc = __shfl(mycomb[0], src);
                else if (j == 1) pc = __shfl(mycomb[1], src);
                else if (j == 2) pc = __shfl(mycomb[2], src);
                else             pc = __shfl(mycomb[3], src);
                switch (np) {
                    case 0: p0 = pc; break; case 1: p1 = pc; break;
                    case 2: p2 = pc; break; default: p3 = pc; break;
                }
                ++np;
                if (np == 4) { flush4(4); np = 0; }
            }
        }
        if (np > 0) flush4(np);
    }

#pragma unroll
    for (int off = 32; off > 0; off >>= 1) facc += __shfl_xor(facc, off);
    if (lane == 0) atomicAdd(out, facc);
}

extern "C" void kernel_launch(void* const* d_in, const int* in_sizes, int n_in,
                              void* d_out, int out_size, void* d_ws, size_t ws_size,
                              hipStream_t stream) {
    const float* R      = (const float*)d_in[0];
    const int*   labels = (const int*)d_in[1];
    float* out = (float*)d_out;

    float*          sq = (float*)d_ws;                               // 16 KB
    unsigned short* Rb = (unsigned short*)((char*)d_ws + 16 * 1024); // 1 MB

    hipLaunchKernelGGL(prep_kernel, dim3(B / 4), dim3(256), 0, stream, R, sq, Rb, out);
    hipLaunchKernelGGL(fused_loss, dim3(B / ROWS), dim3(512), 0, stream,
                       Rb, sq, labels, out);
}

// Round 5
// 132.958 us; speedup vs baseline: 1.2523x; 1.0088x over previous
//
#include <hip/hip_runtime.h>
#include <cstdint>
#include <cstddef>

#define B 4096
#define D 128
#define MARGIN_F 0.2f
#define CW 256            // per-row candidate capacity
#define ROWS 16           // rows per block
#define SSTR 4104         // key-strip stride (ushorts): rows 16B-aligned, bank-skewed

typedef short bf16x8 __attribute__((ext_vector_type(8)));
typedef float f32x4 __attribute__((ext_vector_type(4)));
typedef uint32_t u32x4 __attribute__((ext_vector_type(4)));

// order-preserving float->uint (ascending uint == ascending float)
__device__ __forceinline__ uint32_t xform_key(float f) {
    uint32_t u = __float_as_uint(f);
    return u ^ (uint32_t)((((int32_t)u) >> 31) | 0x80000000);
}
// decode 16-bit truncated key (bucket center under round-to-nearest encode)
__device__ __forceinline__ float unxform16(uint32_t k16) {
    uint32_t u = k16 << 16;
    u = (u & 0x80000000u) ? (u ^ 0x80000000u) : ~u;
    return __uint_as_float(u);
}
__device__ __forceinline__ unsigned short f2bf(float f) {   // round-nearest-even
    uint32_t u = __float_as_uint(f);
    return (unsigned short)((u + 0x7FFFu + ((u >> 16) & 1u)) >> 16);
}

// fused: zero out, sq[i] = ||R[i]||^2, R -> Rb (bf16 rne)
__global__ __launch_bounds__(256) void prep_kernel(const float* __restrict__ R,
                                                   float* __restrict__ sq,
                                                   unsigned short* __restrict__ Rb,
                                                   float* __restrict__ out) {
    if (blockIdx.x == 0 && threadIdx.x == 0) out[0] = 0.0f;
    int wave = threadIdx.x >> 6;
    int lane = threadIdx.x & 63;
    int row  = blockIdx.x * 4 + wave;
    const float2* R2 = (const float2*)R + (size_t)row * (D / 2);
    float2 v = R2[lane];
    ushort2 o; o.x = f2bf(v.x); o.y = f2bf(v.y);
    *(ushort2*)(Rb + (size_t)row * D + lane * 2) = o;
    float s = v.x * v.x + v.y * v.y;
#pragma unroll
    for (int off = 32; off > 0; off >>= 1) s += __shfl_down(s, off);
    if (lane == 0) sq[row] = s;
}

// FUSED: 16 rows/block, 512 threads (8 waves).
// R5: cross-lane serialization removed (R4 lesson: scans were NOT the
// bottleneck; the shared LDS-atomic pipe is the prime suspect):
//  - gather: per-lane 64-bit winner mask + ONE wave prefix-sum -> disjoint
//    store slots. Zero LDS atomics (was ~2400 serialized same-address
//    fetch-adds per CU). cnt[] deleted (count is wave-local).
//  - top-2: per-qq local top-2 (8 ILP chains) + merge, vs 192-op serial chain.
__global__ __launch_bounds__(512) void fused_loss(const unsigned short* __restrict__ Rb,
                                                  const float* __restrict__ sq,
                                                  const int* __restrict__ labels,
                                                  float* __restrict__ out) {
    __shared__ unsigned short S[ROWS * SSTR];      // 131,328 B key strip
    __shared__ uint32_t cand_c[ROWS][CW];          // 16 KB: comb | (match<<31)

    const int tid  = threadIdx.x;
    const int wid  = tid >> 6, lane = tid & 63;
    const int q    = lane >> 4, t = lane & 15;
    const int r0   = blockIdx.x * ROWS;

    // zero cand_c (pad-safety for the chunked rank scan)
    {
        uint32_t* cz = &cand_c[0][0];
#pragma unroll
        for (int c = 0; c < (ROWS * CW) / 512; ++c)
            cz[tid + c * 512] = 0u;
    }

    // ---- phase 1: A fragments for the block's 16 rows (held in registers)
    bf16x8 af[4];
    const unsigned short* baseA = Rb + (size_t)(r0 + t) * D + q * 8;
#pragma unroll
    for (int kq = 0; kq < 4; ++kq)
        af[kq] = *(const bf16x8*)(baseA + kq * 32);

    float sqa[4]; int la[4];                       // epilogue row scalars (row = q*4+rr)
#pragma unroll
    for (int rr = 0; rr < 4; ++rr) {
        sqa[rr] = sq[r0 + q * 4 + rr];
        la[rr]  = labels[r0 + q * 4 + rr];
    }

    // 256 j-tiles of 16 cols; 8 waves -> 32 tiles/wave
    for (int i = 0; i < 32; ++i) {
        const int jt  = wid * 32 + i;
        const int col = jt * 16 + t;
        const unsigned short* baseB = Rb + (size_t)col * D + q * 8;
        bf16x8 bfr[4];
#pragma unroll
        for (int kq = 0; kq < 4; ++kq)
            bfr[kq] = *(const bf16x8*)(baseB + kq * 32);
        f32x4 acc = (f32x4)0.0f;
#pragma unroll
        for (int kq = 0; kq < 4; ++kq)
            acc = __builtin_amdgcn_mfma_f32_16x16x32_bf16(af[kq], bfr[kq], acc, 0, 0, 0);

        const float sqc = sq[col];
        const int   lc  = labels[col];
#pragma unroll
        for (int rr = 0; rr < 4; ++rr) {           // D: row = q*4+rr, col = t
            float g  = acc[rr];
            float d2 = fmaxf(sqa[rr] + sqc - 2.0f * g, 0.0f);
            float dist = (d2 > 0.0f) ? sqrtf(d2) : 0.0f;
            float s = -dist + ((la[rr] == lc) ? 0.0f : MARGIN_F);
            uint32_t key = xform_key(s);           // sim <= 0.2 -> no ovf on +0x8000
            S[(q * 4 + rr) * SSTR + col] = (unsigned short)((key + 0x8000u) >> 16);
        }
    }
    __syncthreads();                               // strip + zeroed cand_c visible

    // ---- phase 2: each wave owns 2 rows
    float facc = 0.0f;
    const int4* lv = (const int4*)labels;

    for (int rr2 = 0; rr2 < 2; ++rr2) {
        const int row  = wid * 2 + rr2;
        const int grow = r0 + row;
        const int li   = labels[grow];

        uint64_t mbits = 0;
        uint32_t t1 = 0, t2 = 0;
        int total = 0;

        {   // kv live range: this scope only (load -> top2/mbits -> gather)
            u32x4 kv[8];
#pragma unroll
            for (int qq = 0; qq < 8; ++qq)
                kv[qq] = *(u32x4*)(&S[row * SSTR + (qq * 64 + lane) * 8]);

            // per-qq local top-2 (8 independent chains) + mbits
            uint32_t t1a[8], t2a[8];
#pragma unroll
            for (int qq = 0; qq < 8; ++qq) {
                const int lb = (qq * 64 + lane) * 2;
                int4 la4 = lv[lb], lc4 = lv[lb + 1];
                uint32_t u[8] = {kv[qq].x & 0xFFFFu, kv[qq].x >> 16,
                                 kv[qq].y & 0xFFFFu, kv[qq].y >> 16,
                                 kv[qq].z & 0xFFFFu, kv[qq].z >> 16,
                                 kv[qq].w & 0xFFFFu, kv[qq].w >> 16};
                uint32_t l1 = 0, l2 = 0;
#pragma unroll
                for (int c = 0; c < 8; ++c) {
                    uint32_t mn = min(l1, u[c]);
                    l1 = max(l1, u[c]);
                    l2 = max(l2, mn);
                }
                t1a[qq] = l1; t2a[qq] = l2;
                mbits |= (uint64_t)(la4.x == li) << (qq * 8 + 0);
                mbits |= (uint64_t)(la4.y == li) << (qq * 8 + 1);
                mbits |= (uint64_t)(la4.z == li) << (qq * 8 + 2);
                mbits |= (uint64_t)(la4.w == li) << (qq * 8 + 3);
                mbits |= (uint64_t)(lc4.x == li) << (qq * 8 + 4);
                mbits |= (uint64_t)(lc4.y == li) << (qq * 8 + 5);
                mbits |= (uint64_t)(lc4.z == li) << (qq * 8 + 6);
                mbits |= (uint64_t)(lc4.w == li) << (qq * 8 + 7);
            }
            // merge the 8 local top-2 pairs
#pragma unroll
            for (int qq = 0; qq < 8; ++qq) {
                uint32_t mn = min(t1, t1a[qq]);
                t1 = max(t1, t1a[qq]);
                t2 = max(t2, mn);
                mn = min(t1, t2a[qq]);
                t1 = max(t1, t2a[qq]);
                t2 = max(t2, mn);
            }

            int kloc = __popcll(mbits);
#pragma unroll
            for (int off = 32; off > 0; off >>= 1) kloc += __shfl_xor(kloc, off);
            const int k0 = kloc;

            // ballot binary search: T = k-th largest of 128-subset
            const int kneed = min(k0, 128);
            uint32_t T = 0;
#pragma unroll
            for (int b = 15; b >= 0; --b) {
                uint32_t g = T | (1u << b);
                int c = __popcll(__ballot(t1 >= g)) + __popcll(__ballot(t2 >= g));
                if (c >= kneed) T = g;
            }

            // gather v2: winner mask -> wave prefix-sum -> disjoint stores
            uint64_t wmask = 0;
#pragma unroll
            for (int qq = 0; qq < 8; ++qq) {
                uint32_t u[8] = {kv[qq].x & 0xFFFFu, kv[qq].x >> 16,
                                 kv[qq].y & 0xFFFFu, kv[qq].y >> 16,
                                 kv[qq].z & 0xFFFFu, kv[qq].z >> 16,
                                 kv[qq].w & 0xFFFFu, kv[qq].w >> 16};
#pragma unroll
                for (int c = 0; c < 8; ++c) {
                    int e = qq * 8 + c;
                    uint32_t m = (uint32_t)((mbits >> e) & 1);
                    wmask |= (uint64_t)((u[c] >= T) | m) << e;
                }
            }
            int cw = __popcll(wmask);
            int inc = cw;
#pragma unroll
            for (int off = 1; off < 64; off <<= 1) {
                int v = __shfl_up(inc, off);
                if (lane >= off) inc += v;
            }
            int mybase = inc - cw;                 // exclusive prefix
            total = __shfl(inc, 63);

#pragma unroll
            for (int qq = 0; qq < 8; ++qq) {
                uint32_t sub = (uint32_t)((wmask >> (qq * 8)) & 0xFFu);
                uint32_t u[8] = {kv[qq].x & 0xFFFFu, kv[qq].x >> 16,
                                 kv[qq].y & 0xFFFFu, kv[qq].y >> 16,
                                 kv[qq].z & 0xFFFFu, kv[qq].z >> 16,
                                 kv[qq].w & 0xFFFFu, kv[qq].w >> 16};
                int jb = (qq * 64 + lane) * 8;
#pragma unroll
                for (int c = 0; c < 8; ++c) {
                    if (sub & (1u << c)) {
                        if (mybase < CW) {
                            uint32_t m = (uint32_t)((mbits >> (qq * 8 + c)) & 1);
                            cand_c[row][mybase] =
                                (u[c] << 12) | (uint32_t)(4095 - (jb + c)) | (m << 31);
                        }
                        ++mybase;
                    }
                }
            }

            t1 = T;                  // carry T out of scope
            t2 = (uint32_t)k0;       // carry k out of scope
        }   // kv dead here

        const uint32_t T = t1;
        const int k = (int)t2;
        const float kf = (float)k;
        const uint32_t combT = T << 12;
        const int ncand = min(total, CW);

        // stores must be visible to the whole wave's LDS reads below
        __builtin_amdgcn_s_waitcnt(0);             // lgkmcnt(0) via builtin arg 0

        // ---- owned candidates -> registers (slots lane, lane+64, +128, +192)
        uint32_t cr0 = cand_c[row][lane];
        uint32_t cr1 = cand_c[row][lane + 64];
        uint32_t cr2 = cand_c[row][lane + 128];
        uint32_t cr3 = cand_c[row][lane + 192];
        uint32_t mycomb[4] = {cr0 & 0x7FFFFFFFu, cr1 & 0x7FFFFFFFu,
                              cr2 & 0x7FFFFFFFu, cr3 & 0x7FFFFFFFu};
        int mym[4]  = {(int)(cr0 >> 31), (int)(cr1 >> 31),
                       (int)(cr2 >> 31), (int)(cr3 >> 31)};
        int myok[4] = {lane < ncand, lane + 64 < ncand,
                       lane + 128 < ncand, lane + 192 < ncand};
        int myc[4]  = {0, 0, 0, 0};

        // ---- exact-rank: chunked broadcast scan (8 cands / 2 b128 per chunk)
        const int npad = (ncand + 7) & ~7;
        for (int c0i = 0; c0i < npad; c0i += 8) {
            u32x4 a = *(const u32x4*)&cand_c[row][c0i];
            u32x4 b = *(const u32x4*)&cand_c[row][c0i + 4];
            uint32_t vv[8] = {a.x, a.y, a.z, a.w, b.x, b.y, b.z, b.w};
#pragma unroll
            for (int e = 0; e < 8; ++e) {
                uint32_t vm = vv[e] & 0x7FFFFFFFu;
#pragma unroll
                for (int j = 0; j < 4; ++j)
                    myc[j] += (vm > mycomb[j]) ? 1 : 0;
            }
        }

        // apply above-T terms per owned candidate (each owned by one lane)
#pragma unroll
        for (int j = 0; j < 4; ++j) {
            if (myok[j] && mycomb[j] >= combT) {
                int rank = 1 + myc[j];
                float v = unxform16(mycomb[j] >> 12);
                if (!mym[j] && rank <= k)
                    facc += v * (0.5f + ((kf - (float)rank + 1.0f) / kf) * 0.5f);
                else if (mym[j] && rank > k)
                    facc -= v * (0.5f + (((float)rank - kf) / (float)(B - k)) * 0.5f);
            }
        }

        // ---- below-T matches (rank > k guaranteed): detect from registers,
        // extract via ballot, flush up to 4 pivots per strip re-scan
        uint32_t p0 = 0xFFFFFFFFu, p1 = 0xFFFFFFFFu, p2 = 0xFFFFFFFFu, p3 = 0xFFFFFFFFu;

        auto flush4 = [&](int npv) {
            int c0 = 0, c1 = 0, c2 = 0, c3 = 0;
#pragma unroll
            for (int qq = 0; qq < 8; ++qq) {
                u32x4 kq = *(const u32x4*)(&S[row * SSTR + (qq * 64 + lane) * 8]);
                uint32_t u[8] = {kq.x & 0xFFFFu, kq.x >> 16,
                                 kq.y & 0xFFFFu, kq.y >> 16,
                                 kq.z & 0xFFFFu, kq.z >> 16,
                                 kq.w & 0xFFFFu, kq.w >> 16};
                int jb = (qq * 64 + lane) * 8;
#pragma unroll
                for (int cc = 0; cc < 8; ++cc) {
                    uint32_t ce = (u[cc] << 12) | (uint32_t)(4095 - (jb + cc));
                    c0 += (ce > p0) ? 1 : 0;  c1 += (ce > p1) ? 1 : 0;
                    c2 += (ce > p2) ? 1 : 0;  c3 += (ce > p3) ? 1 : 0;
                }
            }
#pragma unroll
            for (int off = 32; off > 0; off >>= 1) {
                c0 += __shfl_xor(c0, off); c1 += __shfl_xor(c1, off);
                c2 += __shfl_xor(c2, off); c3 += __shfl_xor(c3, off);
            }
            if (lane == 0) {
                if (npv > 0) facc -= unxform16(p0 >> 12) * (0.5f + (((float)(1 + c0) - kf) / (float)(B - k)) * 0.5f);
                if (npv > 1) facc -= unxform16(p1 >> 12) * (0.5f + (((float)(1 + c1) - kf) / (float)(B - k)) * 0.5f);
                if (npv > 2) facc -= unxform16(p2 >> 12) * (0.5f + (((float)(1 + c2) - kf) / (float)(B - k)) * 0.5f);
                if (npv > 3) facc -= unxform16(p3 >> 12) * (0.5f + (((float)(1 + c3) - kf) / (float)(B - k)) * 0.5f);
            }
            p0 = p1 = p2 = p3 = 0xFFFFFFFFu;
        };

        int np = 0;
#pragma unroll
        for (int j = 0; j < 4; ++j) {
            uint64_t mg = __ballot(myok[j] && mym[j] && (mycomb[j] < combT));
            while (mg) {
                int src = __ffsll((unsigned long long)mg) - 1;
                mg &= mg - 1;
                uint32_t pc;
                if (j == 0)      pc = __shfl(mycomb[0], src);
                else if (j == 1) pc = __shfl(mycomb[1], src);
                else if (j == 2) pc = __shfl(mycomb[2], src);
                else             pc = __shfl(mycomb[3], src);
                switch (np) {
                    case 0: p0 = pc; break; case 1: p1 = pc; break;
                    case 2: p2 = pc; break; default: p3 = pc; break;
                }
                ++np;
                if (np == 4) { flush4(4); np = 0; }
            }
        }
        if (np > 0) flush4(np);
    }

#pragma unroll
    for (int off = 32; off > 0; off >>= 1) facc += __shfl_xor(facc, off);
    if (lane == 0) atomicAdd(out, facc);
}

extern "C" void kernel_launch(void* const* d_in, const int* in_sizes, int n_in,
                              void* d_out, int out_size, void* d_ws, size_t ws_size,
                              hipStream_t stream) {
    const float* R      = (const float*)d_in[0];
    const int*   labels = (const int*)d_in[1];
    float* out = (float*)d_out;

    float*          sq = (float*)d_ws;                               // 16 KB
    unsigned short* Rb = (unsigned short*)((char*)d_ws + 16 * 1024); // 1 MB

    hipLaunchKernelGGL(prep_kernel, dim3(B / 4), dim3(256), 0, stream, R, sq, Rb, out);
    hipLaunchKernelGGL(fused_loss, dim3(B / ROWS), dim3(512), 0, stream,
                       Rb, sq, labels, out);
}